// Round 1
// baseline (139.749 us; speedup 1.0000x reference)
//
#include <hip/hip_runtime.h>

// CatNet_76553497084407 — SLAYER-style spiking CNN, fully collapsed over time.
//
// Every if_spikes() gets a time-constant drive (sum_t/T) and every layer is
// linear per timestep with time-kernel 1, so only spike COUNTS flow between
// layers. The T=50 spike-train dimension never needs to be materialized.
//
// Pipeline per sample n (all in LDS, one block per n):
//   xbar[180]  = sum_t x[n,0,h,0,t]
//   a1 = conv1(xbar)/T + b1          (k=3, pad=1, 1->16)   -> rate -> r1[16,180]
//   a2 = conv2(r1) + b2              (k=9, pad=1, 16->32)  -> rate -> r2[32,174]
//   a3 = 1.1*(r2[:,0::2]+r2[:,1::2])                       -> rate -> r3[32,87]
//   a4 = conv3(r3) + b3              (k=7, pad=1, 32->32)  -> rate -> r4[32,83]
//   out[n,o] = sum_{c,h} r4*wf[o] + bf[o]
//
// rate(a): IF neuron, 50 steps, exact f32 reference order:
//   v += a; s = (v >= 0.9999f); v -= s*0.9999f;  rate = count/50.0f

#define T_STEPS 50
#define THETA   0.9999f

template<int W>
__device__ __forceinline__ void spike_rate_w(const float* a, float* r) {
    float v[W], c[W];
#pragma unroll
    for (int w = 0; w < W; ++w) { v[w] = 0.f; c[w] = 0.f; }
#pragma unroll
    for (int k = 0; k < T_STEPS; ++k) {
#pragma unroll
        for (int w = 0; w < W; ++w) {
            v[w] += a[w];
            float s = (v[w] >= THETA) ? 1.0f : 0.0f;
            v[w] -= s * THETA;
            c[w] += s;
        }
    }
#pragma unroll
    for (int w = 0; w < W; ++w) r[w] = c[w] / 50.0f;  // true divide: match sum/T
}

__device__ __forceinline__ float spike_rate1(float a) {
    float r;
    spike_rate_w<1>(&a, &r);
    return r;
}

extern "C" __global__ void __launch_bounds__(512)
catnet_kernel(const float* __restrict__ x,
              const float* __restrict__ w1, const float* __restrict__ b1,
              const float* __restrict__ w2, const float* __restrict__ b2,
              const float* __restrict__ w3, const float* __restrict__ b3,
              const float* __restrict__ wf, const float* __restrict__ bf,
              float* __restrict__ out)
{
    const int n   = blockIdx.x;
    const int tid = threadIdx.x;

    // padded LDS buffers (pad = zero border for the pad=1 convs)
    __shared__ float xbar[182];        // [h+1], h in [0,180)
    __shared__ float r1p[16][182];     // [c][h+1]
    __shared__ float r2s[32][174];
    __shared__ float r3p[32][89];      // [c][h+1], h in [0,87)
    __shared__ float r4s[32][83];

    // zero conv pads
    if (tid < 16)                { r1p[tid][0] = 0.f; r1p[tid][181] = 0.f; }
    if (tid >= 32 && tid < 64)   { r3p[tid-32][0] = 0.f; r3p[tid-32][88] = 0.f; }
    if (tid == 64)               { xbar[0] = 0.f; xbar[181] = 0.f; }

    // ---- phase 0: time-sum of input (x layout [N,1,180,1,50]) ----
    const float* xn = x + (size_t)n * (180 * 50);
    for (int h = tid; h < 180; h += 512) {
        const float* row = xn + h * 50;
        float s = 0.f;
#pragma unroll
        for (int t = 0; t < T_STEPS; ++t) s += row[t];
        xbar[h + 1] = s;
    }
    __syncthreads();

    // ---- phase 1: conv1 (1->16, k=3, pad=1), /T, +b1, rate ----
    for (int idx = tid; idx < 16 * 180; idx += 512) {
        int c = idx / 180, h = idx - c * 180;
        float a = w1[c*3+0] * xbar[h] + w1[c*3+1] * xbar[h+1] + w1[c*3+2] * xbar[h+2];
        a = a / 50.0f + b1[c];
        r1p[c][h + 1] = spike_rate1(a);
    }
    __syncthreads();

    // ---- phase 2: conv2 (16->32, k=9, pad=1) + rate; 4 out-chans/thread ----
    for (int idx = tid; idx < 8 * 174; idx += 512) {
        int cg = idx / 174, h = idx - cg * 174;   // c2 = cg*4 + j
        float a[4];
#pragma unroll
        for (int j = 0; j < 4; ++j) a[j] = b2[cg*4 + j];
#pragma unroll
        for (int ci = 0; ci < 16; ++ci) {
#pragma unroll
            for (int kh = 0; kh < 9; ++kh) {
                float rv = r1p[ci][h + kh];
#pragma unroll
                for (int j = 0; j < 4; ++j)
                    a[j] += w2[((cg*4 + j)*16 + ci)*9 + kh] * rv;
            }
        }
        float r[4];
        spike_rate_w<4>(a, r);
#pragma unroll
        for (int j = 0; j < 4; ++j) r2s[cg*4 + j][h] = r[j];
    }
    __syncthreads();

    // ---- phase 3: sum-pool(2,1) * 1.1 + rate ----
    for (int idx = tid; idx < 32 * 87; idx += 512) {
        int c = idx / 87, h = idx - c * 87;
        float a = 1.1f * (r2s[c][2*h] + r2s[c][2*h + 1]);
        r3p[c][h + 1] = spike_rate1(a);
    }
    __syncthreads();

    // ---- phase 4: conv3 (32->32, k=7, pad=1) + rate; 4 out-chans/thread ----
    for (int idx = tid; idx < 8 * 83; idx += 512) {
        int cg = idx / 83, h = idx - cg * 83;     // c2 = cg*4 + j
        float a[4];
#pragma unroll
        for (int j = 0; j < 4; ++j) a[j] = b3[cg*4 + j];
#pragma unroll
        for (int ci = 0; ci < 32; ++ci) {
#pragma unroll
            for (int kh = 0; kh < 7; ++kh) {
                float rv = r3p[ci][h + kh];
#pragma unroll
                for (int j = 0; j < 4; ++j)
                    a[j] += w3[((cg*4 + j)*32 + ci)*7 + kh] * rv;
            }
        }
        float r[4];
        spike_rate_w<4>(a, r);
#pragma unroll
        for (int j = 0; j < 4; ++j) r4s[cg*4 + j][h] = r[j];
    }
    __syncthreads();

    // ---- phase 5: dense [32*83] -> 4 outputs; one wave per output ----
    if (tid < 256) {
        const int wave = tid >> 6;     // o = wave (4 waves)
        const int lane = tid & 63;
        const int o = wave;
        const float* r4f = &r4s[0][0];          // [32][83] flat
        const float* wo  = wf + o * (32 * 83);  // wf[o][c][h][0] flat, same layout
        float acc = 0.f;
        for (int j = lane; j < 32 * 83; j += 64)
            acc += r4f[j] * wo[j];
#pragma unroll
        for (int off = 32; off > 0; off >>= 1)
            acc += __shfl_down(acc, off, 64);
        if (lane == 0) out[n * 4 + o] = acc + bf[o];
    }
}

extern "C" void kernel_launch(void* const* d_in, const int* in_sizes, int n_in,
                              void* d_out, int out_size, void* d_ws, size_t ws_size,
                              hipStream_t stream) {
    const float* x  = (const float*)d_in[0];
    const float* w1 = (const float*)d_in[1];
    const float* b1 = (const float*)d_in[2];
    const float* w2 = (const float*)d_in[3];
    const float* b2 = (const float*)d_in[4];
    const float* w3 = (const float*)d_in[5];
    const float* b3 = (const float*)d_in[6];
    const float* wf = (const float*)d_in[7];
    const float* bf = (const float*)d_in[8];
    float* outp = (float*)d_out;

    catnet_kernel<<<dim3(256), dim3(512), 0, stream>>>(
        x, w1, b1, w2, b2, w3, b3, wf, bf, outp);
}

// Round 2
// 118.970 us; speedup vs baseline: 1.1747x; 1.1747x over previous
//
#include <hip/hip_runtime.h>

// CatNet_76553497084407 — SLAYER-style spiking CNN, fully collapsed over time.
//
// Only spike COUNTS flow between layers (time-constant drive through linear
// per-timestep ops), so the T=50 dimension is never materialized.
//
// R2: 1024-thread blocks (16 waves/CU, 2x occupancy), wave-uniform channel
// mapping in conv2/conv3 (weights via scalar SMEM loads), coalesced phase 0.

#define T_STEPS 50
#define THETA   0.9999f

template<int W>
__device__ __forceinline__ void spike_rate_w(const float* a, float* r) {
    float v[W], c[W];
#pragma unroll
    for (int w = 0; w < W; ++w) { v[w] = 0.f; c[w] = 0.f; }
#pragma unroll
    for (int k = 0; k < T_STEPS; ++k) {
#pragma unroll
        for (int w = 0; w < W; ++w) {
            v[w] += a[w];
            float s = (v[w] >= THETA) ? 1.0f : 0.0f;
            v[w] -= s * THETA;
            c[w] += s;
        }
    }
#pragma unroll
    for (int w = 0; w < W; ++w) r[w] = c[w] / 50.0f;  // true divide: match sum/T
}

__device__ __forceinline__ float spike_rate1(float a) {
    float r;
    spike_rate_w<1>(&a, &r);
    return r;
}

extern "C" __global__ void __launch_bounds__(1024)
catnet_kernel(const float* __restrict__ x,
              const float* __restrict__ w1, const float* __restrict__ b1,
              const float* __restrict__ w2, const float* __restrict__ b2,
              const float* __restrict__ w3, const float* __restrict__ b3,
              const float* __restrict__ wf, const float* __restrict__ bf,
              float* __restrict__ out)
{
    const int n    = blockIdx.x;
    const int tid  = threadIdx.x;
    const int wave = tid >> 6;
    const int lane = tid & 63;

    __shared__ float xbar[182];        // [h+1], h in [0,180)
    __shared__ float r1p[16][182];     // [c][h+1]  (zero-padded borders)
    __shared__ float r2s[32][174];
    __shared__ float r3p[32][89];      // [c][h+1], h in [0,87)
    __shared__ float r4s[32][83];
    __shared__ float part[16];

    // zero conv pads
    if (tid < 16)              { r1p[tid][0] = 0.f; r1p[tid][181] = 0.f; }
    if (tid >= 32 && tid < 64) { r3p[tid-32][0] = 0.f; r3p[tid-32][88] = 0.f; }
    if (tid == 64)             { xbar[0] = 0.f; xbar[181] = 0.f; }

    // ---- phase 0: time-sum of input, 4 lanes per h (coalesced-ish) ----
    const float* xn = x + (size_t)n * (180 * 50);
    if (tid < 720) {
        const int h = tid >> 2, q = tid & 3;
        const float* row = xn + h * 50;
        float s = 0.f;
        for (int t = q; t < T_STEPS; t += 4) s += row[t];
        s += __shfl_xor(s, 1, 4);
        s += __shfl_xor(s, 2, 4);
        if (q == 0) xbar[h + 1] = s;
    }
    __syncthreads();

    // ---- phase 1: conv1 (1->16, k=3, pad=1), /T, +b1, rate ----
    for (int idx = tid; idx < 16 * 180; idx += 1024) {
        int c = idx / 180, h = idx - c * 180;
        float a = w1[c*3+0] * xbar[h] + w1[c*3+1] * xbar[h+1] + w1[c*3+2] * xbar[h+2];
        a = a / 50.0f + b1[c];
        r1p[c][h + 1] = spike_rate1(a);
    }
    __syncthreads();

    // ---- phase 2: conv2 (16->32, k=9, pad=1) + rate ----
    // wave -> (channel-group cg of 4 out-ch, h-half); lanes -> h. Weight
    // addresses are wave-uniform -> scalar (SMEM) loads via readfirstlane.
    {
        const int ucg   = __builtin_amdgcn_readfirstlane(wave >> 1);   // 0..7
        const int half  = wave & 1;
        const int hbase = half * 87;
        const int h0 = hbase + lane;            // always valid (lane<64<=87)
        const int h1 = hbase + 64 + lane;       // valid iff lane < 23
        const bool v1 = lane < 23;
        const int h1r = v1 ? h1 : h0;
        const float* wb = w2 + ucg * 4 * 144;   // [j][ci][kh], j stride 144

        float a[8];
#pragma unroll
        for (int j = 0; j < 4; ++j) { a[j] = b2[ucg*4 + j]; a[4+j] = a[j]; }

        for (int ci = 0; ci < 16; ++ci) {
            float r0[9], r1v[9];
#pragma unroll
            for (int kh = 0; kh < 9; ++kh) {
                r0[kh]  = r1p[ci][h0 + kh];
                r1v[kh] = r1p[ci][h1r + kh];
            }
#pragma unroll
            for (int j = 0; j < 4; ++j) {
                const float* wj = wb + j * 144 + ci * 9;
#pragma unroll
                for (int kh = 0; kh < 9; ++kh) {
                    float wv = wj[kh];
                    a[j]   += wv * r0[kh];
                    a[4+j] += wv * r1v[kh];
                }
            }
        }
        float r[8];
        spike_rate_w<8>(a, r);
#pragma unroll
        for (int j = 0; j < 4; ++j) {
            r2s[ucg*4 + j][h0] = r[j];
            if (v1) r2s[ucg*4 + j][h1] = r[4+j];
        }
    }
    __syncthreads();

    // ---- phase 3: sum-pool(2,1) * 1.1 + rate ----
    for (int idx = tid; idx < 32 * 87; idx += 1024) {
        int c = idx / 87, h = idx - c * 87;
        float a = 1.1f * (r2s[c][2*h] + r2s[c][2*h + 1]);
        r3p[c][h + 1] = spike_rate1(a);
    }
    __syncthreads();

    // ---- phase 4: conv3 (32->32, k=7, pad=1) + rate ----
    {
        const int ucg   = __builtin_amdgcn_readfirstlane(wave >> 1);   // 0..7
        const int half  = wave & 1;
        const int hbase = half * 42;            // half0: h 0..41, half1: 42..82
        const int cnt   = half ? 41 : 42;
        const bool v0   = lane < cnt;
        const int h0    = hbase + (v0 ? lane : 0);
        const float* wb = w3 + ucg * 4 * 224;   // [j][ci][kh], j stride 224

        float a[4];
#pragma unroll
        for (int j = 0; j < 4; ++j) a[j] = b3[ucg*4 + j];

        for (int ci = 0; ci < 32; ++ci) {
            float rv[7];
#pragma unroll
            for (int kh = 0; kh < 7; ++kh) rv[kh] = r3p[ci][h0 + kh];
#pragma unroll
            for (int j = 0; j < 4; ++j) {
                const float* wj = wb + j * 224 + ci * 7;
#pragma unroll
                for (int kh = 0; kh < 7; ++kh)
                    a[j] += wj[kh] * rv[kh];
            }
        }
        float r[4];
        spike_rate_w<4>(a, r);
        if (v0) {
#pragma unroll
            for (int j = 0; j < 4; ++j) r4s[ucg*4 + j][h0] = r[j];
        }
    }
    __syncthreads();

    // ---- phase 5: dense [32*83] -> 4 outputs; 4 waves per output ----
    {
        const int o = wave >> 2, q = wave & 3;
        const float* r4f = &r4s[0][0];
        const float* wo  = wf + o * (32 * 83);
        float acc = 0.f;
        for (int j = q * 64 + lane; j < 32 * 83; j += 256)
            acc += r4f[j] * wo[j];
#pragma unroll
        for (int off = 32; off > 0; off >>= 1)
            acc += __shfl_down(acc, off, 64);
        if (lane == 0) part[wave] = acc;
    }
    __syncthreads();
    if (tid < 4) {
        float s = part[tid*4] + part[tid*4+1] + part[tid*4+2] + part[tid*4+3];
        out[n * 4 + tid] = s + bf[tid];
    }
}

extern "C" void kernel_launch(void* const* d_in, const int* in_sizes, int n_in,
                              void* d_out, int out_size, void* d_ws, size_t ws_size,
                              hipStream_t stream) {
    const float* x  = (const float*)d_in[0];
    const float* w1 = (const float*)d_in[1];
    const float* b1 = (const float*)d_in[2];
    const float* w2 = (const float*)d_in[3];
    const float* b2 = (const float*)d_in[4];
    const float* w3 = (const float*)d_in[5];
    const float* b3 = (const float*)d_in[6];
    const float* wf = (const float*)d_in[7];
    const float* bf = (const float*)d_in[8];
    float* outp = (float*)d_out;

    catnet_kernel<<<dim3(256), dim3(1024), 0, stream>>>(
        x, w1, b1, w2, b2, w3, b3, wf, bf, outp);
}

// Round 3
// 105.934 us; speedup vs baseline: 1.3192x; 1.1231x over previous
//
#include <hip/hip_runtime.h>

// CatNet_76553497084407 — SLAYER-style spiking CNN, fully collapsed over time.
//
// Only spike COUNTS flow between layers (time-constant drive through linear
// per-timestep ops), so the T=50 dimension is never materialized.
//
// R3: guarded closed-form IF count. For constant drive a, exact-arith count is
// clamp(floor(50*a/theta), 0, 50). The f32 sequential reference can differ
// only when t = 50a/theta is within ~3e-5 of an integer; we fall back to the
// exact 50-step sim (wave-collective, per neuron slot) when |t - rint(t)| <
// 5e-4 (15x safety margin). Outputs are bit-identical to the full sim.

#define T_STEPS 50
#define THETA   0.9999f

__device__ __forceinline__ float spike_rate(float a) {
    constexpr float INV = 50.0f / 0.9999f;   // one f32 rounding of 50/theta
    float t = a * INV;
    float c = fminf(fmaxf(floorf(t), 0.0f), 50.0f);
    // risky: t could straddle an integer boundary vs the sequential f32 sim.
    bool risky = (t > 0.5f) && (fabsf(t - rintf(t)) < 5e-4f);
    if (__ballot(risky)) {
        float v = 0.f, cnt = 0.f;
#pragma unroll 1
        for (int k = 0; k < T_STEPS; ++k) {
            v += a;
            float s = (v >= THETA) ? 1.0f : 0.0f;
            v -= s * THETA;
            cnt += s;
        }
        c = cnt;   // sim == closed form for non-risky lanes; use sim for all
    }
    return c / 50.0f;   // true divide: match reference sum/T rounding
}

extern "C" __global__ void __launch_bounds__(1024)
catnet_kernel(const float* __restrict__ x,
              const float* __restrict__ w1, const float* __restrict__ b1,
              const float* __restrict__ w2, const float* __restrict__ b2,
              const float* __restrict__ w3, const float* __restrict__ b3,
              const float* __restrict__ wf, const float* __restrict__ bf,
              float* __restrict__ out)
{
    const int n    = blockIdx.x;
    const int tid  = threadIdx.x;
    const int wave = tid >> 6;
    const int lane = tid & 63;

    __shared__ float xbar[182];        // [h+1], h in [0,180)
    __shared__ float r1p[16][182];     // [c][h+1]  (zero-padded borders)
    __shared__ float r2s[32][174];
    __shared__ float r3p[32][89];      // [c][h+1], h in [0,87)
    __shared__ float r4s[32][83];
    __shared__ float part[16];

    // zero conv pads
    if (tid < 16)              { r1p[tid][0] = 0.f; r1p[tid][181] = 0.f; }
    if (tid >= 32 && tid < 64) { r3p[tid-32][0] = 0.f; r3p[tid-32][88] = 0.f; }
    if (tid == 64)             { xbar[0] = 0.f; xbar[181] = 0.f; }

    // ---- phase 0: time-sum of input, 4 lanes per h ----
    const float* xn = x + (size_t)n * (180 * 50);
    if (tid < 720) {
        const int h = tid >> 2, q = tid & 3;
        const float* row = xn + h * 50;
        float s = 0.f;
        for (int t = q; t < T_STEPS; t += 4) s += row[t];
        s += __shfl_xor(s, 1, 4);
        s += __shfl_xor(s, 2, 4);
        if (q == 0) xbar[h + 1] = s;
    }
    __syncthreads();

    // ---- phase 1: conv1 (1->16, k=3, pad=1), /T, +b1, rate ----
    for (int idx = tid; idx < 16 * 180; idx += 1024) {
        int c = idx / 180, h = idx - c * 180;
        float a = w1[c*3+0] * xbar[h] + w1[c*3+1] * xbar[h+1] + w1[c*3+2] * xbar[h+2];
        a = a / 50.0f + b1[c];
        r1p[c][h + 1] = spike_rate(a);
    }
    __syncthreads();

    // ---- phase 2: conv2 (16->32, k=9, pad=1) + rate ----
    // wave -> (4-out-ch group, h-half); lanes -> h. Weights wave-uniform ->
    // scalar SMEM loads.
    {
        const int ucg   = __builtin_amdgcn_readfirstlane(wave >> 1);   // 0..7
        const int half  = wave & 1;
        const int hbase = half * 87;
        const int h0 = hbase + lane;
        const int h1 = hbase + 64 + lane;       // valid iff lane < 23
        const bool v1 = lane < 23;
        const int h1r = v1 ? h1 : h0;
        const float* wb = w2 + ucg * 4 * 144;   // [j][ci][kh], j stride 144

        float a[8];
#pragma unroll
        for (int j = 0; j < 4; ++j) { a[j] = b2[ucg*4 + j]; a[4+j] = a[j]; }

        for (int ci = 0; ci < 16; ++ci) {
            float r0[9], r1v[9];
#pragma unroll
            for (int kh = 0; kh < 9; ++kh) {
                r0[kh]  = r1p[ci][h0 + kh];
                r1v[kh] = r1p[ci][h1r + kh];
            }
#pragma unroll
            for (int j = 0; j < 4; ++j) {
                const float* wj = wb + j * 144 + ci * 9;
#pragma unroll
                for (int kh = 0; kh < 9; ++kh) {
                    float wv = wj[kh];
                    a[j]   += wv * r0[kh];
                    a[4+j] += wv * r1v[kh];
                }
            }
        }
#pragma unroll
        for (int j = 0; j < 4; ++j) {
            r2s[ucg*4 + j][h0] = spike_rate(a[j]);
            float rj = spike_rate(a[4+j]);
            if (v1) r2s[ucg*4 + j][h1] = rj;
        }
    }
    __syncthreads();

    // ---- phase 3: sum-pool(2,1) * 1.1 + rate ----
    for (int idx = tid; idx < 32 * 87; idx += 1024) {
        int c = idx / 87, h = idx - c * 87;
        float a = 1.1f * (r2s[c][2*h] + r2s[c][2*h + 1]);
        r3p[c][h + 1] = spike_rate(a);
    }
    __syncthreads();

    // ---- phase 4: conv3 (32->32, k=7, pad=1) + rate ----
    {
        const int ucg   = __builtin_amdgcn_readfirstlane(wave >> 1);   // 0..7
        const int half  = wave & 1;
        const int hbase = half * 42;            // half0: h 0..41, half1: 42..82
        const int cnt   = half ? 41 : 42;
        const bool v0   = lane < cnt;
        const int h0    = hbase + (v0 ? lane : 0);
        const float* wb = w3 + ucg * 4 * 224;   // [j][ci][kh], j stride 224

        float a[4];
#pragma unroll
        for (int j = 0; j < 4; ++j) a[j] = b3[ucg*4 + j];

        for (int ci = 0; ci < 32; ++ci) {
            float rv[7];
#pragma unroll
            for (int kh = 0; kh < 7; ++kh) rv[kh] = r3p[ci][h0 + kh];
#pragma unroll
            for (int j = 0; j < 4; ++j) {
                const float* wj = wb + j * 224 + ci * 7;
#pragma unroll
                for (int kh = 0; kh < 7; ++kh)
                    a[j] += wj[kh] * rv[kh];
            }
        }
#pragma unroll
        for (int j = 0; j < 4; ++j) {
            float rj = spike_rate(a[j]);
            if (v0) r4s[ucg*4 + j][h0] = rj;
        }
    }
    __syncthreads();

    // ---- phase 5: dense [32*83] -> 4 outputs; 4 waves per output ----
    {
        const int o = wave >> 2, q = wave & 3;
        const float* r4f = &r4s[0][0];
        const float* wo  = wf + o * (32 * 83);
        float acc = 0.f;
        for (int j = q * 64 + lane; j < 32 * 83; j += 256)
            acc += r4f[j] * wo[j];
#pragma unroll
        for (int off = 32; off > 0; off >>= 1)
            acc += __shfl_down(acc, off, 64);
        if (lane == 0) part[wave] = acc;
    }
    __syncthreads();
    if (tid < 4) {
        float s = part[tid*4] + part[tid*4+1] + part[tid*4+2] + part[tid*4+3];
        out[n * 4 + tid] = s + bf[tid];
    }
}

extern "C" void kernel_launch(void* const* d_in, const int* in_sizes, int n_in,
                              void* d_out, int out_size, void* d_ws, size_t ws_size,
                              hipStream_t stream) {
    const float* x  = (const float*)d_in[0];
    const float* w1 = (const float*)d_in[1];
    const float* b1 = (const float*)d_in[2];
    const float* w2 = (const float*)d_in[3];
    const float* b2 = (const float*)d_in[4];
    const float* w3 = (const float*)d_in[5];
    const float* b3 = (const float*)d_in[6];
    const float* wf = (const float*)d_in[7];
    const float* bf = (const float*)d_in[8];
    float* outp = (float*)d_out;

    catnet_kernel<<<dim3(256), dim3(1024), 0, stream>>>(
        x, w1, b1, w2, b2, w3, b3, wf, bf, outp);
}